// Round 4
// baseline (3023.451 us; speedup 1.0000x reference)
//
#include <hip/hip_runtime.h>

typedef unsigned short u16;
typedef unsigned int u32;
typedef __bf16 bf16x8 __attribute__((ext_vector_type(8)));
typedef float f32x4 __attribute__((ext_vector_type(4)));
typedef u16 u16x8 __attribute__((ext_vector_type(8)));
typedef u16 u16x4 __attribute__((ext_vector_type(4)));

#define IN_CH 256
#define HID 64
#define BSHIFT 8            // 256 nodes per bucket
#define BNODES 256
#define NBUK 391            // ceil(100000 / 256)
#define BCAP 10240          // avg 8184 edges/bucket; +22 sigma headroom
#define TILE 8192           // edges per partition tile

__device__ __forceinline__ u16 f2bf(float f) {
  union { float f; unsigned u; } v; v.f = f;
  unsigned r = v.u + 0x7FFFu + ((v.u >> 16) & 1u);  // RNE
  return (u16)(r >> 16);
}
__device__ __forceinline__ float bf2f(u16 h) {
  union { unsigned u; float f; } v; v.u = ((unsigned)h) << 16;
  return v.f;
}

// transpose + bf16-convert weights: w1t[n][k] (64x256), w2t[n][k] (64x64)
__global__ void k_wprep(const float* __restrict__ W1, const float* __restrict__ W2,
                        u16* __restrict__ w1t, u16* __restrict__ w2t) {
  int t = blockIdx.x * blockDim.x + threadIdx.x;
  if (t < 64 * 256) {
    int n = t >> 8, k = t & 255;
    w1t[t] = f2bf(W1[k * 64 + n]);
  }
  int t2 = t - 64 * 256;
  if (t2 >= 0 && t2 < 64 * 64) {
    int n = t2 >> 6, k = t2 & 63;
    w2t[t2] = f2bf(W2[k * 64 + n]);
  }
}

// ---------------- phase A: LDS-staged bucket partition ----------------
// Edge packed as u32: src (bits 0-19) | dloc (bits 20-27). Int LDS atomics only.
// Bucket-internal order is arbitrary (no dst sort needed anymore).

__global__ __launch_bounds__(1024) void k_part(const int* __restrict__ e_src,
                                               const int* __restrict__ e_dst,
                                               int* __restrict__ bcnt,
                                               u32* __restrict__ bedge, int E) {
  __shared__ int lcnt[512];
  __shared__ int lscan[512];
  __shared__ int gbase[512];
  __shared__ int wsum[8];
  __shared__ u32 stag[TILE];
  __shared__ int dest[TILE];
  int t = threadIdx.x;
  int base = blockIdx.x * TILE;
  int here = E - base; if (here > TILE) here = TILE;

  if (t < 512) lcnt[t] = 0;
  __syncthreads();

  u32 m[8]; int bk[8]; int rk[8];
#pragma unroll
  for (int k = 0; k < 8; ++k) {
    int e = base + t + k * 1024;
    if (e < E) {
      int s = e_src[e], d = e_dst[e];
      bk[k] = d >> BSHIFT;
      m[k] = (u32)s | ((u32)(d & (BNODES - 1)) << 20);
      rk[k] = atomicAdd(&lcnt[bk[k]], 1);
    } else bk[k] = -1;
  }
  __syncthreads();

  // exclusive scan of lcnt[0..511] by threads 0..511 (8 waves)
  int lane = t & 63, w = t >> 6;
  int v = 0, x = 0;
  if (t < 512) { v = lcnt[t]; x = v; }
#pragma unroll
  for (int off = 1; off < 64; off <<= 1) {
    int y = __shfl_up(x, off);
    if (lane >= off) x += y;
  }
  if (t < 512 && lane == 63) wsum[w] = x;
  __syncthreads();
  if (t < 512) {
    int wo = 0;
    for (int i = 0; i < w; ++i) wo += wsum[i];
    lscan[t] = x - v + wo;
  }
  __syncthreads();

  // reserve global space per bucket
  if (t < NBUK) gbase[t] = t * BCAP + atomicAdd(&bcnt[t], lcnt[t]);
  __syncthreads();

  // place into LDS staging ordered by bucket
#pragma unroll
  for (int k = 0; k < 8; ++k) {
    if (bk[k] >= 0) {
      int p = lscan[bk[k]] + rk[k];
      stag[p] = m[k];
      dest[p] = gbase[bk[k]] + rk[k];
    }
  }
  __syncthreads();

  // coalesced copy-out (runs of same-bucket edges are contiguous)
#pragma unroll
  for (int k = 0; k < 8; ++k) {
    int p = t + k * 1024;
    if (p < here) bedge[dest[p]] = stag[p];
  }
}

// ---------------- k_deg: per-node in-degree -> dinv (replaces k_sort) ----------------
// Only product gemm1 needs before agg; the counting sort itself is eliminated
// because the fused bucket-agg accumulates in LDS and doesn't need dst-grouped runs.

__global__ __launch_bounds__(1024) void k_deg(const int* __restrict__ bcnt,
                                              const u32* __restrict__ bedge,
                                              float* __restrict__ dinv, int N) {
  __shared__ int hist[BNODES];
  int b = blockIdx.x, t = threadIdx.x;
  if (t < BNODES) hist[t] = 0;
  __syncthreads();
  int n = bcnt[b]; if (n > BCAP) n = BCAP;
  const u32* be = bedge + (size_t)b * BCAP;
  for (int i = t; i < n; i += 1024) atomicAdd(&hist[be[i] >> 20], 1);
  __syncthreads();
  if (t < BNODES) {
    int node = (b << BSHIFT) + t;
    if (node < N) dinv[node] = rsqrtf((float)(hist[t] + 1));  // +1 self-loop
  }
}

// ---------------- gemm1 (MFMA 16x16x32 bf16), wave = 16 rows x ALL 64 cols ----------------
// A[m=lane&15][k=quad*8+j], B[n=lane&15][k=quad*8+j], D: col=lane&15, row=quad*4+reg.
// h'[row] = dinv[row] * (x@W1)[row].  Standard [N][64] output layout.
// launch_bounds(256,1): frees the register allocator so the 16 hoisted A-loads
// stay clustered (earlier: default occupancy target serialized them).

__global__ __launch_bounds__(256, 1) void k_gemm1(const float* __restrict__ x,
                                                  const u16* __restrict__ w1t,
                                                  const float* __restrict__ dinv,
                                                  u16* __restrict__ h1, int N) {
  int lane = threadIdx.x & 63;
  int wave = threadIdx.x >> 6;
  int rowbase = (blockIdx.x * 4 + wave) * 16;
  if (rowbase >= N) return;  // N % 16 == 0: tiles never straddle
  int mn = lane & 15, quad = lane >> 4;
  const float* arow = x + (size_t)(rowbase + mn) * IN_CH + quad * 8;

  // hoist all 16 A loads (64 VGPR) -> one vmcnt wait
  float4 a[16];
#pragma unroll
  for (int kc = 0; kc < 8; ++kc) {
    a[2 * kc] = *(const float4*)(arow + kc * 32);
    a[2 * kc + 1] = *(const float4*)(arow + kc * 32 + 4);
  }
  // convert once to bf16 frags (32 VGPR)
  u16x8 au[8];
#pragma unroll
  for (int kc = 0; kc < 8; ++kc) {
    float4 a0 = a[2 * kc], a1 = a[2 * kc + 1];
    au[kc][0] = f2bf(a0.x); au[kc][1] = f2bf(a0.y);
    au[kc][2] = f2bf(a0.z); au[kc][3] = f2bf(a0.w);
    au[kc][4] = f2bf(a1.x); au[kc][5] = f2bf(a1.y);
    au[kc][6] = f2bf(a1.z); au[kc][7] = f2bf(a1.w);
  }

  f32x4 acc[4] = {{0.f, 0.f, 0.f, 0.f}, {0.f, 0.f, 0.f, 0.f},
                  {0.f, 0.f, 0.f, 0.f}, {0.f, 0.f, 0.f, 0.f}};
#pragma unroll
  for (int c = 0; c < 4; ++c) {
    const u16* brow = w1t + (c * 16 + mn) * IN_CH + quad * 8;
    u16x8 bu[8];  // clustered, L1-hot (B is 32 KB shared chip-wide)
#pragma unroll
    for (int kc = 0; kc < 8; ++kc) bu[kc] = *(const u16x8*)(brow + kc * 32);
#pragma unroll
    for (int kc = 0; kc < 8; ++kc)
      acc[c] = __builtin_amdgcn_mfma_f32_16x16x32_bf16(
          __builtin_bit_cast(bf16x8, au[kc]), __builtin_bit_cast(bf16x8, bu[kc]),
          acc[c], 0, 0, 0);
  }
#pragma unroll
  for (int r = 0; r < 4; ++r) {
    int row = rowbase + quad * 4 + r;
    float dv = dinv[row];
#pragma unroll
    for (int c = 0; c < 4; ++c)
      h1[(size_t)row * HID + c * 16 + mn] = f2bf(dv * acc[c][r]);
  }
}

__global__ __launch_bounds__(256) void k_gemm2(const u16* __restrict__ g1,
                                               const u16* __restrict__ w2t,
                                               const float* __restrict__ dinv,
                                               u16* __restrict__ h2) {
  int lane = threadIdx.x & 63;
  int wave = threadIdx.x >> 6;
  int rowbase = blockIdx.x * 16;
  int colbase = wave * 16;
  int mn = lane & 15, quad = lane >> 4;
  const u16* arow = g1 + (size_t)(rowbase + mn) * HID + quad * 8;
  const u16* brow = w2t + (colbase + mn) * HID + quad * 8;
  u16x8 au0 = *(const u16x8*)(arow);
  u16x8 au1 = *(const u16x8*)(arow + 32);
  u16x8 bu0 = *(const u16x8*)(brow);
  u16x8 bu1 = *(const u16x8*)(brow + 32);
  f32x4 acc = {0.f, 0.f, 0.f, 0.f};
  acc = __builtin_amdgcn_mfma_f32_16x16x32_bf16(
      __builtin_bit_cast(bf16x8, au0), __builtin_bit_cast(bf16x8, bu0), acc, 0, 0, 0);
  acc = __builtin_amdgcn_mfma_f32_16x16x32_bf16(
      __builtin_bit_cast(bf16x8, au1), __builtin_bit_cast(bf16x8, bu1), acc, 0, 0, 0);
#pragma unroll
  for (int r = 0; r < 4; ++r) {
    int row = rowbase + quad * 4 + r;
    h2[(size_t)row * HID + colbase + mn] = f2bf(dinv[row] * acc[r]);
  }
}

// ---------------- fused bucket-major aggregation ----------------
// out[i] = dinv_i * (sum_e h'[src_e] + h'[i]) + bias
// Round-3 lesson: agg gather floor = L2 transaction count (~100G trans/s);
// full 128-B row per edge (2x64-B transactions) is the minimum-transaction
// pattern, ~60 us/pass. This kernel keeps that pattern but eliminates the
// counting sort: block per dst-bucket, 64-KB f32 LDS accumulator acc[256][64],
// edges consumed in ARBITRARY order via ds_add_f32. Self rows seed acc.
// launch_bounds(1024,8): VGPR<=64 so 2 blocks (128 KB LDS, 32 waves) per CU.

template <bool RELU, bool BF16OUT>
__global__ __launch_bounds__(1024, 8) void k_aggb(const u16* __restrict__ hin,
                                                  const int* __restrict__ bcnt,
                                                  const u32* __restrict__ bedge,
                                                  const float* __restrict__ dinv,
                                                  const float* __restrict__ bias,
                                                  void* __restrict__ outv, int N) {
  __shared__ float acc[BNODES * HID];  // 64 KB
  int b = blockIdx.x, t = threadIdx.x;
  int wave = t >> 6, lane = t & 63;
  int base = b << BSHIFT;
  int n = bcnt[b]; if (n > BCAP) n = BCAP;
  const u32* se = bedge + (size_t)b * BCAP;

  // seed acc with self rows (streamed, coalesced 128-B reads)
#pragma unroll
  for (int i = 0; i < 16; ++i) {
    int node = wave * 16 + i;
    int gn = base + node;
    float v = 0.f;
    if (gn < N) v = bf2f(hin[(size_t)gn * HID + lane]);
    acc[node * HID + lane] = v;
  }
  __syncthreads();

  // edge loop: wave grabs 64 edges (one coalesced dword load), broadcasts each
  // via readlane, gathers the full 128-B h row (64 lanes x 2 B), ds_add_f32.
  for (int b2 = wave * 64; b2 < n; b2 += 1024) {
    int cnt = n - b2; if (cnt > 64) cnt = 64;
    u32 ew = (lane < cnt) ? se[b2 + lane] : 0u;
    if (cnt == 64) {
#pragma unroll
      for (int kk = 0; kk < 4; ++kk) {
        u16 hv[16]; int dl[16];
#pragma unroll
        for (int k = 0; k < 16; ++k) {
          u32 m = __shfl(ew, kk * 16 + k);
          dl[k] = (int)(m >> 20);
          hv[k] = hin[(size_t)(m & 0xFFFFF) * HID + lane];
        }
#pragma unroll
        for (int k = 0; k < 16; ++k)
          atomicAdd(&acc[dl[k] * HID + lane], bf2f(hv[k]));
      }
    } else {
      for (int k = 0; k < cnt; ++k) {
        u32 m = __shfl(ew, k);
        float f = bf2f(hin[(size_t)(m & 0xFFFFF) * HID + lane]);
        atomicAdd(&acc[(int)(m >> 20) * HID + lane], f);
      }
    }
  }
  __syncthreads();

  // epilogue: scale + bias (+relu), coalesced stores
  float bv = bias[lane];
#pragma unroll
  for (int i = 0; i < 16; ++i) {
    int node = wave * 16 + i;
    int gn = base + node;
    if (gn < N) {
      float v = dinv[gn] * acc[node * HID + lane] + bv;
      if (RELU) v = fmaxf(v, 0.f);
      if (BF16OUT) ((u16*)outv)[(size_t)gn * HID + lane] = f2bf(v);
      else ((float*)outv)[(size_t)gn * HID + lane] = v;
    }
  }
}

// ---------------- host ----------------

extern "C" void kernel_launch(void* const* d_in, const int* in_sizes, int n_in,
                              void* d_out, int out_size, void* d_ws, size_t ws_size,
                              hipStream_t stream) {
  const float* x = (const float*)d_in[0];
  const int* ei = (const int*)d_in[1];  // [2][E] int32
  const float* W1 = (const float*)d_in[2];
  const float* b1 = (const float*)d_in[3];
  const float* W2 = (const float*)d_in[4];
  const float* b2 = (const float*)d_in[5];
  float* out = (float*)d_out;

  const int N = in_sizes[0] / IN_CH;  // 100000
  const int E = in_sizes[1] / 2;      // 3200000
  const int* e_src = ei;
  const int* e_dst = ei + E;

  size_t off = 0;
  auto carve = [&](size_t bytes) -> char* {
    char* p = (char*)d_ws + off;
    off += (bytes + 255) & ~(size_t)255;
    return p;
  };
  int* bcnt = (int*)carve((size_t)NBUK * 4);
  u32* bedge = (u32*)carve((size_t)NBUK * BCAP * 4);  // 16 MB
  float* dinv = (float*)carve((size_t)N * 4);
  u16* w1t = (u16*)carve(64 * 256 * 2);
  u16* w2t = (u16*)carve(64 * 64 * 2);
  u16* h1 = (u16*)carve((size_t)N * HID * 2);  // reused for h2
  u16* g1 = (u16*)carve((size_t)N * HID * 2);

  const int n_tiles = (E + TILE - 1) / TILE;  // 391
  const int nb_g1 = (N + 63) / 64;            // 64 rows per block (4 waves x 16)

  hipMemsetAsync(bcnt, 0, (size_t)NBUK * 4, stream);
  k_wprep<<<(64 * 256 + 64 * 64 + 255) / 256, 256, 0, stream>>>(W1, W2, w1t, w2t);
  k_part<<<n_tiles, 1024, 0, stream>>>(e_src, e_dst, bcnt, bedge, E);
  k_deg<<<NBUK, 1024, 0, stream>>>(bcnt, bedge, dinv, N);
  k_gemm1<<<nb_g1, 256, 0, stream>>>(x, w1t, dinv, h1, N);
  k_aggb<true, true><<<NBUK, 1024, 0, stream>>>(h1, bcnt, bedge, dinv, b1, g1, N);
  k_gemm2<<<N / 16, 256, 0, stream>>>(g1, w2t, dinv, h1);
  k_aggb<false, false><<<NBUK, 1024, 0, stream>>>(h1, bcnt, bedge, dinv, b2, out, N);
}

// Round 5
// 359.510 us; speedup vs baseline: 8.4099x; 8.4099x over previous
//
#include <hip/hip_runtime.h>

typedef unsigned short u16;
typedef unsigned int u32;
typedef __bf16 bf16x8 __attribute__((ext_vector_type(8)));
typedef float f32x4 __attribute__((ext_vector_type(4)));
typedef u16 u16x8 __attribute__((ext_vector_type(8)));

#define IN_CH 256
#define HID 64
#define BSHIFT 8            // 256 nodes per bucket
#define BNODES 256
#define NBUK 391            // ceil(100000 / 256)
#define BCAP 10240          // avg 8184 edges/bucket; +22 sigma headroom
#define TILE 8192           // edges per partition tile

__device__ __forceinline__ u16 f2bf(float f) {
  union { float f; unsigned u; } v; v.f = f;
  unsigned r = v.u + 0x7FFFu + ((v.u >> 16) & 1u);  // RNE
  return (u16)(r >> 16);
}
__device__ __forceinline__ float bf2f(u16 h) {
  union { unsigned u; float f; } v; v.u = ((unsigned)h) << 16;
  return v.f;
}

// transpose + bf16-convert W1 only: w1t[n][k] (64x256). W2 is consumed fp32 by k_agg2.
__global__ void k_wprep(const float* __restrict__ W1, u16* __restrict__ w1t) {
  int t = blockIdx.x * blockDim.x + threadIdx.x;
  if (t < 64 * 256) {
    int n = t >> 8, k = t & 255;
    w1t[t] = f2bf(W1[k * 64 + n]);
  }
}

// ---------------- phase A: LDS-staged bucket partition ----------------
// Edge packed as u32: src (bits 0-19) | dloc (bits 20-27). Int LDS atomics only.

__global__ __launch_bounds__(1024) void k_part(const int* __restrict__ e_src,
                                               const int* __restrict__ e_dst,
                                               int* __restrict__ bcnt,
                                               u32* __restrict__ bedge, int E) {
  __shared__ int lcnt[512];
  __shared__ int lscan[512];
  __shared__ int gbase[512];
  __shared__ int wsum[8];
  __shared__ u32 stag[TILE];
  __shared__ int dest[TILE];
  int t = threadIdx.x;
  int base = blockIdx.x * TILE;
  int here = E - base; if (here > TILE) here = TILE;

  if (t < 512) lcnt[t] = 0;
  __syncthreads();

  u32 m[8]; int bk[8]; int rk[8];
#pragma unroll
  for (int k = 0; k < 8; ++k) {
    int e = base + t + k * 1024;
    if (e < E) {
      int s = e_src[e], d = e_dst[e];
      bk[k] = d >> BSHIFT;
      m[k] = (u32)s | ((u32)(d & (BNODES - 1)) << 20);
      rk[k] = atomicAdd(&lcnt[bk[k]], 1);
    } else bk[k] = -1;
  }
  __syncthreads();

  // exclusive scan of lcnt[0..511] by threads 0..511 (8 waves)
  int lane = t & 63, w = t >> 6;
  int v = 0, x = 0;
  if (t < 512) { v = lcnt[t]; x = v; }
#pragma unroll
  for (int off = 1; off < 64; off <<= 1) {
    int y = __shfl_up(x, off);
    if (lane >= off) x += y;
  }
  if (t < 512 && lane == 63) wsum[w] = x;
  __syncthreads();
  if (t < 512) {
    int wo = 0;
    for (int i = 0; i < w; ++i) wo += wsum[i];
    lscan[t] = x - v + wo;
  }
  __syncthreads();

  // reserve global space per bucket
  if (t < NBUK) gbase[t] = t * BCAP + atomicAdd(&bcnt[t], lcnt[t]);
  __syncthreads();

  // place into LDS staging ordered by bucket
#pragma unroll
  for (int k = 0; k < 8; ++k) {
    if (bk[k] >= 0) {
      int p = lscan[bk[k]] + rk[k];
      stag[p] = m[k];
      dest[p] = gbase[bk[k]] + rk[k];
    }
  }
  __syncthreads();

  // coalesced copy-out (runs of same-bucket edges are contiguous)
#pragma unroll
  for (int k = 0; k < 8; ++k) {
    int p = t + k * 1024;
    if (p < here) bedge[dest[p]] = stag[p];
  }
}

// ---------------- phase B: per-bucket counting sort by dst (in-place) ----------------
// Emits rptr/rcnt/dinv. Int LDS atomics only.

__global__ __launch_bounds__(1024) void k_sort(const int* __restrict__ bcnt,
                                               u32* __restrict__ bedge,
                                               int* __restrict__ rptr,
                                               int* __restrict__ rcnt,
                                               float* __restrict__ dinv, int N) {
  __shared__ u32 stag[BCAP];     // 40 KB
  __shared__ int hist[BNODES];
  __shared__ int cur[BNODES];
  __shared__ int wsum4[4];
  int b = blockIdx.x, t = threadIdx.x;
  if (t < BNODES) hist[t] = 0;
  __syncthreads();
  int n = bcnt[b]; if (n > BCAP) n = BCAP;
  u32* be = bedge + (size_t)b * BCAP;

  for (int i = t; i < n; i += 1024) atomicAdd(&hist[be[i] >> 20], 1);
  __syncthreads();

  // exclusive scan of hist[0..255] by threads 0..255 (4 waves)
  int lane = t & 63, w = t >> 6;
  int v = 0, x = 0;
  if (t < BNODES) { v = hist[t]; x = v; }
#pragma unroll
  for (int off = 1; off < 64; off <<= 1) {
    int y = __shfl_up(x, off);
    if (lane >= off) x += y;
  }
  if (t < BNODES && lane == 63) wsum4[w] = x;
  __syncthreads();
  if (t < BNODES) {
    int wo = 0;
    for (int i = 0; i < w; ++i) wo += wsum4[i];
    int ex = x - v + wo;
    cur[t] = ex;
    int node = (b << BSHIFT) + t;
    if (node < N) {
      rptr[node] = b * BCAP + ex;
      rcnt[node] = v;
      dinv[node] = rsqrtf((float)(v + 1));  // +1 self-loop
    }
  }
  __syncthreads();

  // rank + scatter into LDS (sorted by dloc)
  for (int i = t; i < n; i += 1024) {
    u32 m = be[i];
    int p = atomicAdd(&cur[m >> 20], 1);
    stag[p] = m;
  }
  __syncthreads();

  // in-place coalesced writeback
  for (int i = t; i < n; i += 1024) be[i] = stag[i];
}

// ---------------- gemm1 (MFMA 16x16x32 bf16), wave = 16 rows x ALL 64 cols ----------------
// A[m=lane&15][k=quad*8+j], B[n=lane&15][k=quad*8+j], D: col=lane&15, row=quad*4+reg.
// h'[row] = dinv[row] * (x@W1)[row].
// launch_bounds(256,1): frees the register allocator so the 16 hoisted A-loads
// stay clustered (round 6 of prior session: tighter bound serialized them).

__global__ __launch_bounds__(256, 1) void k_gemm1(const float* __restrict__ x,
                                                  const u16* __restrict__ w1t,
                                                  const float* __restrict__ dinv,
                                                  u16* __restrict__ h1, int N) {
  int lane = threadIdx.x & 63;
  int wave = threadIdx.x >> 6;
  int rowbase = (blockIdx.x * 4 + wave) * 16;
  if (rowbase >= N) return;  // N % 16 == 0: tiles never straddle
  int mn = lane & 15, quad = lane >> 4;
  const float* arow = x + (size_t)(rowbase + mn) * IN_CH + quad * 8;

  // hoist all 16 A loads (64 VGPR) -> one vmcnt wait
  float4 a[16];
#pragma unroll
  for (int kc = 0; kc < 8; ++kc) {
    a[2 * kc] = *(const float4*)(arow + kc * 32);
    a[2 * kc + 1] = *(const float4*)(arow + kc * 32 + 4);
  }
  // convert once to bf16 frags (32 VGPR)
  u16x8 au[8];
#pragma unroll
  for (int kc = 0; kc < 8; ++kc) {
    float4 a0 = a[2 * kc], a1 = a[2 * kc + 1];
    au[kc][0] = f2bf(a0.x); au[kc][1] = f2bf(a0.y);
    au[kc][2] = f2bf(a0.z); au[kc][3] = f2bf(a0.w);
    au[kc][4] = f2bf(a1.x); au[kc][5] = f2bf(a1.y);
    au[kc][6] = f2bf(a1.z); au[kc][7] = f2bf(a1.w);
  }

  f32x4 acc[4] = {{0.f, 0.f, 0.f, 0.f}, {0.f, 0.f, 0.f, 0.f},
                  {0.f, 0.f, 0.f, 0.f}, {0.f, 0.f, 0.f, 0.f}};
#pragma unroll
  for (int c = 0; c < 4; ++c) {
    const u16* brow = w1t + (c * 16 + mn) * IN_CH + quad * 8;
    u16x8 bu[8];  // clustered, L1-hot (B is 32 KB shared chip-wide)
#pragma unroll
    for (int kc = 0; kc < 8; ++kc) bu[kc] = *(const u16x8*)(brow + kc * 32);
#pragma unroll
    for (int kc = 0; kc < 8; ++kc)
      acc[c] = __builtin_amdgcn_mfma_f32_16x16x32_bf16(
          __builtin_bit_cast(bf16x8, au[kc]), __builtin_bit_cast(bf16x8, bu[kc]),
          acc[c], 0, 0, 0);
  }
#pragma unroll
  for (int r = 0; r < 4; ++r) {
    int row = rowbase + quad * 4 + r;
    float dv = dinv[row];
#pragma unroll
    for (int c = 0; c < 4; ++c)
      h1[(size_t)row * HID + c * 16 + mn] = f2bf(dv * acc[c][r]);
  }
}

// ---------------- agg pass 1: wave per node, scalar edges, multi-accumulator ----------------
// u[i] = dinv_i * relu( dinv_i * (sum_e h'[src_e] + h'[i]) + b1 )
// The extra dinv_i factor pre-applies the SOURCE-side norm for layer 2, so pass 2
// can aggregate u rows directly and fold @W2 into its epilogue (gemm2 eliminated;
// aggregation is linear: out = dinv_i*((sum u[s] + u[i])@W2) + b2).
// launch_bounds(256,4): <=128 VGPR; measured VGPR=20, no spill.

__global__ __launch_bounds__(256, 4) void k_agg1(const u16* __restrict__ hin,
                                                 const int* __restrict__ rptr,
                                                 const int* __restrict__ rcnt,
                                                 const u32* __restrict__ sedge,
                                                 const float* __restrict__ bias,
                                                 u16* __restrict__ outu, int N) {
  int wid = blockIdx.x * 4 + (threadIdx.x >> 6);
  int lane = threadIdx.x & 63;
  if (wid >= N) return;
  int start = __builtin_amdgcn_readfirstlane(rptr[wid]);
  int len = __builtin_amdgcn_readfirstlane(rcnt[wid]);
  float di = rsqrtf((float)(len + 1));
  float a0 = bf2f(hin[(size_t)wid * HID + lane]);  // self-loop
  float a1 = 0.f, a2 = 0.f, a3 = 0.f;
  const u32* se = sedge + start;
  int j = 0;
  for (; j + 16 <= len; j += 16) {
    u16 v[16];
#pragma unroll
    for (int k = 0; k < 16; ++k) {
      int e = (int)(se[j + k] & 0xFFFFF);  // wave-uniform -> s_load batch
      v[k] = hin[(size_t)e * HID + lane];  // 16 gathers in flight
    }
#pragma unroll
    for (int k = 0; k < 16; ++k) {
      float f = bf2f(v[k]);
      if ((k & 3) == 0) a0 += f;
      else if ((k & 3) == 1) a1 += f;
      else if ((k & 3) == 2) a2 += f;
      else a3 += f;
    }
  }
  if (j + 8 <= len) {
    u16 v[8];
#pragma unroll
    for (int k = 0; k < 8; ++k) {
      int e = (int)(se[j + k] & 0xFFFFF);
      v[k] = hin[(size_t)e * HID + lane];
    }
#pragma unroll
    for (int k = 0; k < 8; ++k) {
      float f = bf2f(v[k]);
      if ((k & 3) == 0) a0 += f;
      else if ((k & 3) == 1) a1 += f;
      else if ((k & 3) == 2) a2 += f;
      else a3 += f;
    }
    j += 8;
  }
  if (j + 4 <= len) {
    u16 v[4];
#pragma unroll
    for (int k = 0; k < 4; ++k) {
      int e = (int)(se[j + k] & 0xFFFFF);
      v[k] = hin[(size_t)e * HID + lane];
    }
    a0 += bf2f(v[0]); a1 += bf2f(v[1]); a2 += bf2f(v[2]); a3 += bf2f(v[3]);
    j += 4;
  }
  for (; j < len; ++j) {
    int e = (int)(se[j] & 0xFFFFF);
    a0 += bf2f(hin[(size_t)e * HID + lane]);
  }
  float acc = (a0 + a1) + (a2 + a3);
  acc = di * acc + bias[lane];
  acc = fmaxf(acc, 0.f);                 // relu
  outu[(size_t)wid * HID + lane] = f2bf(di * acc);  // pre-scaled u row
}

// ---------------- agg pass 2 + fused W2: 16 waves/block, wave per node ----------------
// out[i] = dinv_i * ((sum_e u[src_e] + u[i]) @ W2) + b2
// Same gather loop (same L2/L3 transaction floor). Epilogue: stage the wave's
// 64-f32 row to LDS, each lane dots against its W2 column (bf16 LDS copy, 8 KB,
// loaded once per 16-node block -> W2 L2 traffic ~50 MB total). LDS reads:
// rowbuf[wave][k] is a broadcast, w2s[k*64+lane] is stride-1 -> conflict-free.

__global__ __launch_bounds__(1024, 4) void k_agg2(const u16* __restrict__ u1,
                                                  const int* __restrict__ rptr,
                                                  const int* __restrict__ rcnt,
                                                  const u32* __restrict__ sedge,
                                                  const float* __restrict__ W2,
                                                  const float* __restrict__ b2,
                                                  float* __restrict__ out, int N) {
  __shared__ u16 w2s[HID * HID];        // 8 KB, layout [k][n] (= W2 row-major)
  __shared__ float rowbuf[16][HID];     // 4 KB
  int t = threadIdx.x;
  for (int i = t; i < HID * HID; i += 1024) w2s[i] = f2bf(W2[i]);
  __syncthreads();
  int wave = t >> 6, lane = t & 63;
  int wid = blockIdx.x * 16 + wave;
  if (wid >= N) return;  // N % 16 == 0: never taken at N=100000
  int start = __builtin_amdgcn_readfirstlane(rptr[wid]);
  int len = __builtin_amdgcn_readfirstlane(rcnt[wid]);
  float di = rsqrtf((float)(len + 1));
  float a0 = bf2f(u1[(size_t)wid * HID + lane]);  // self-loop u row
  float a1 = 0.f, a2 = 0.f, a3 = 0.f;
  const u32* se = sedge + start;
  int j = 0;
  for (; j + 16 <= len; j += 16) {
    u16 v[16];
#pragma unroll
    for (int k = 0; k < 16; ++k) {
      int e = (int)(se[j + k] & 0xFFFFF);
      v[k] = u1[(size_t)e * HID + lane];
    }
#pragma unroll
    for (int k = 0; k < 16; ++k) {
      float f = bf2f(v[k]);
      if ((k & 3) == 0) a0 += f;
      else if ((k & 3) == 1) a1 += f;
      else if ((k & 3) == 2) a2 += f;
      else a3 += f;
    }
  }
  if (j + 8 <= len) {
    u16 v[8];
#pragma unroll
    for (int k = 0; k < 8; ++k) {
      int e = (int)(se[j + k] & 0xFFFFF);
      v[k] = u1[(size_t)e * HID + lane];
    }
#pragma unroll
    for (int k = 0; k < 8; ++k) {
      float f = bf2f(v[k]);
      if ((k & 3) == 0) a0 += f;
      else if ((k & 3) == 1) a1 += f;
      else if ((k & 3) == 2) a2 += f;
      else a3 += f;
    }
    j += 8;
  }
  if (j + 4 <= len) {
    u16 v[4];
#pragma unroll
    for (int k = 0; k < 4; ++k) {
      int e = (int)(se[j + k] & 0xFFFFF);
      v[k] = u1[(size_t)e * HID + lane];
    }
    a0 += bf2f(v[0]); a1 += bf2f(v[1]); a2 += bf2f(v[2]); a3 += bf2f(v[3]);
    j += 4;
  }
  for (; j < len; ++j) {
    int e = (int)(se[j] & 0xFFFFF);
    a0 += bf2f(u1[(size_t)e * HID + lane]);
  }
  float acc = (a0 + a1) + (a2 + a3);

  // fused @W2: stage row (wave-local; compiler inserts the lgkmcnt dep-wait)
  rowbuf[wave][lane] = acc;
  float o = 0.f;
#pragma unroll 8
  for (int k = 0; k < HID; ++k)
    o += rowbuf[wave][k] * bf2f(w2s[k * HID + lane]);
  out[(size_t)wid * HID + lane] = di * o + b2[lane];
}

// ---------------- host ----------------

extern "C" void kernel_launch(void* const* d_in, const int* in_sizes, int n_in,
                              void* d_out, int out_size, void* d_ws, size_t ws_size,
                              hipStream_t stream) {
  const float* x = (const float*)d_in[0];
  const int* ei = (const int*)d_in[1];  // [2][E] int32
  const float* W1 = (const float*)d_in[2];
  const float* b1 = (const float*)d_in[3];
  const float* W2 = (const float*)d_in[4];
  const float* b2 = (const float*)d_in[5];
  float* out = (float*)d_out;

  const int N = in_sizes[0] / IN_CH;  // 100000
  const int E = in_sizes[1] / 2;      // 3200000
  const int* e_src = ei;
  const int* e_dst = ei + E;

  size_t off = 0;
  auto carve = [&](size_t bytes) -> char* {
    char* p = (char*)d_ws + off;
    off += (bytes + 255) & ~(size_t)255;
    return p;
  };
  int* bcnt = (int*)carve((size_t)NBUK * 4);
  u32* bedge = (u32*)carve((size_t)NBUK * BCAP * 4);  // 16 MB
  int* rptr = (int*)carve((size_t)N * 4);
  int* rcnt = (int*)carve((size_t)N * 4);
  float* dinv = (float*)carve((size_t)N * 4);
  u16* w1t = (u16*)carve(64 * 256 * 2);
  u16* h1 = (u16*)carve((size_t)N * HID * 2);
  u16* u1 = (u16*)carve((size_t)N * HID * 2);

  const int n_tiles = (E + TILE - 1) / TILE;  // 391
  const int nb_g1 = (N + 63) / 64;            // 64 rows per block (4 waves x 16)

  hipMemsetAsync(bcnt, 0, (size_t)NBUK * 4, stream);
  k_wprep<<<(64 * 256 + 255) / 256, 256, 0, stream>>>(W1, w1t);
  k_part<<<n_tiles, 1024, 0, stream>>>(e_src, e_dst, bcnt, bedge, E);
  k_sort<<<NBUK, 1024, 0, stream>>>(bcnt, bedge, rptr, rcnt, dinv, N);
  k_gemm1<<<nb_g1, 256, 0, stream>>>(x, w1t, dinv, h1, N);
  k_agg1<<<(N + 3) / 4, 256, 0, stream>>>(h1, rptr, rcnt, bedge, b1, u1, N);
  k_agg2<<<(N + 15) / 16, 1024, 0, stream>>>(u1, rptr, rcnt, bedge, W2, b2, out, N);
}

// Round 8
// 346.561 us; speedup vs baseline: 8.7241x; 1.0374x over previous
//
#include <hip/hip_runtime.h>

typedef unsigned short u16;
typedef unsigned int u32;
typedef __bf16 bf16x8 __attribute__((ext_vector_type(8)));
typedef float f32x4 __attribute__((ext_vector_type(4)));
typedef u16 u16x8 __attribute__((ext_vector_type(8)));

#define IN_CH 256
#define HID 64
#define BSHIFT 7            // 128 nodes per bucket
#define BNODES 128
#define NBUK 782            // ceil(100000 / 128)
#define BCAP 5632           // mean 4092 edges/bucket; +24 sigma headroom
#define TILE 8192           // edges per partition tile

__device__ __forceinline__ u16 f2bf(float f) {
  union { float f; unsigned u; } v; v.f = f;
  unsigned r = v.u + 0x7FFFu + ((v.u >> 16) & 1u);  // RNE
  return (u16)(r >> 16);
}
__device__ __forceinline__ float bf2f(u16 h) {
  union { unsigned u; float f; } v; v.u = ((unsigned)h) << 16;
  return v.f;
}

// transpose + bf16-convert weights: w1t[n][k] (64x256), w2t[n][k] (64x64)
__global__ void k_wprep(const float* __restrict__ W1, const float* __restrict__ W2,
                        u16* __restrict__ w1t, u16* __restrict__ w2t) {
  int t = blockIdx.x * blockDim.x + threadIdx.x;
  if (t < 64 * 256) {
    int n = t >> 8, k = t & 255;
    w1t[t] = f2bf(W1[k * 64 + n]);
  }
  int t2 = t - 64 * 256;
  if (t2 >= 0 && t2 < 64 * 64) {
    int n = t2 >> 6, k = t2 & 63;
    w2t[t2] = f2bf(W2[k * 64 + n]);
  }
}

// ---------------- phase A: LDS-staged bucket partition (128-node buckets) ----------------
// Edge packed as u32: src (bits 0-19) | dloc (bits 20-26). Validated correct in
// round-7's initial check (absmax 1.95e-3 before the aggb nondeterminism hit).

__global__ __launch_bounds__(1024) void k_part(const int* __restrict__ e_src,
                                               const int* __restrict__ e_dst,
                                               int* __restrict__ bcnt,
                                               u32* __restrict__ bedge, int E) {
  __shared__ int lcnt[1024];
  __shared__ int lscan[1024];
  __shared__ int gbase[1024];
  __shared__ int wsum[16];
  __shared__ u32 stag[TILE];
  __shared__ int dest[TILE];
  int t = threadIdx.x;
  int base = blockIdx.x * TILE;
  int here = E - base; if (here > TILE) here = TILE;

  lcnt[t] = 0;
  __syncthreads();

  u32 m[8]; int bk[8]; int rk[8];
#pragma unroll
  for (int k = 0; k < 8; ++k) {
    int e = base + t + k * 1024;
    if (e < E) {
      int s = e_src[e], d = e_dst[e];
      bk[k] = d >> BSHIFT;
      m[k] = (u32)s | ((u32)(d & (BNODES - 1)) << 20);
      rk[k] = atomicAdd(&lcnt[bk[k]], 1);
    } else bk[k] = -1;
  }
  __syncthreads();

  // exclusive scan of lcnt[0..1023] (16 waves)
  int lane = t & 63, w = t >> 6;
  int v = lcnt[t], x = v;
#pragma unroll
  for (int off = 1; off < 64; off <<= 1) {
    int y = __shfl_up(x, off);
    if (lane >= off) x += y;
  }
  if (lane == 63) wsum[w] = x;
  __syncthreads();
  {
    int wo = 0;
    for (int i = 0; i < w; ++i) wo += wsum[i];
    lscan[t] = x - v + wo;
  }
  __syncthreads();

  // reserve global space per bucket
  if (t < NBUK) gbase[t] = t * BCAP + atomicAdd(&bcnt[t], lcnt[t]);
  __syncthreads();

  // place into LDS staging ordered by bucket
#pragma unroll
  for (int k = 0; k < 8; ++k) {
    if (bk[k] >= 0) {
      int p = lscan[bk[k]] + rk[k];
      stag[p] = m[k];
      dest[p] = gbase[bk[k]] + rk[k];
    }
  }
  __syncthreads();

  // coalesced copy-out (runs of same-bucket edges are contiguous)
#pragma unroll
  for (int k = 0; k < 8; ++k) {
    int p = t + k * 1024;
    if (p < here) bedge[dest[p]] = stag[p];
  }
}

// ---------------- phase B: per-bucket counting sort by dst (in-place) ----------------
// Emits rptr/rcnt/dinv. Round-7 geometry fix: 782 buckets x 512 threads x 24 KB
// LDS -> 4 blocks/CU, ALL 782 blocks resident in one round (vs 391x1024x46KB =
// 2/CU), and half the serial edges per block. Same algorithm as the proven 347us
// version otherwise.

__global__ __launch_bounds__(512) void k_sort(const int* __restrict__ bcnt,
                                              u32* __restrict__ bedge,
                                              int* __restrict__ rptr,
                                              int* __restrict__ rcnt,
                                              float* __restrict__ dinv, int N) {
  __shared__ u32 stag[BCAP];     // 22 KB
  __shared__ int hist[BNODES];
  __shared__ int cur[BNODES];
  __shared__ int wsum2[2];
  int b = blockIdx.x, t = threadIdx.x;
  if (t < BNODES) hist[t] = 0;
  __syncthreads();
  int n = bcnt[b]; if (n > BCAP) n = BCAP;
  u32* be = bedge + (size_t)b * BCAP;

  for (int i = t; i < n; i += 512) atomicAdd(&hist[be[i] >> 20], 1);
  __syncthreads();

  // exclusive scan of hist[0..127] by threads 0..127 (2 waves)
  int lane = t & 63, w = t >> 6;
  int v = 0, x = 0;
  if (t < BNODES) { v = hist[t]; x = v; }
#pragma unroll
  for (int off = 1; off < 64; off <<= 1) {
    int y = __shfl_up(x, off);
    if (lane >= off) x += y;
  }
  if (t < BNODES && lane == 63) wsum2[w] = x;
  __syncthreads();
  if (t < BNODES) {
    int wo = (w == 1) ? wsum2[0] : 0;
    int ex = x - v + wo;
    cur[t] = ex;
    int node = (b << BSHIFT) + t;
    if (node < N) {
      rptr[node] = b * BCAP + ex;
      rcnt[node] = v;
      dinv[node] = rsqrtf((float)(v + 1));  // +1 self-loop
    }
  }
  __syncthreads();

  // rank + scatter into LDS (sorted by dloc)
  for (int i = t; i < n; i += 512) {
    u32 m = be[i];
    int p = atomicAdd(&cur[m >> 20], 1);
    stag[p] = m;
  }
  __syncthreads();

  // in-place coalesced writeback
  for (int i = t; i < n; i += 512) be[i] = stag[i];
}

// ---------------- gemm1 (MFMA 16x16x32 bf16), wave = 16 rows x ALL 64 cols ----------------
// A[m=lane&15][k=quad*8+j], B[n=lane&15][k=quad*8+j], D: col=lane&15, row=quad*4+reg.
// h'[row] = dinv[row] * (x@W1)[row].
// launch_bounds(256,1): frees the register allocator so the 16 hoisted A-loads
// stay clustered (tighter bound previously serialized them -> latency-bound).

__global__ __launch_bounds__(256, 1) void k_gemm1(const float* __restrict__ x,
                                                  const u16* __restrict__ w1t,
                                                  const float* __restrict__ dinv,
                                                  u16* __restrict__ h1, int N) {
  int lane = threadIdx.x & 63;
  int wave = threadIdx.x >> 6;
  int rowbase = (blockIdx.x * 4 + wave) * 16;
  if (rowbase >= N) return;  // N % 16 == 0: tiles never straddle
  int mn = lane & 15, quad = lane >> 4;
  const float* arow = x + (size_t)(rowbase + mn) * IN_CH + quad * 8;

  // hoist all 16 A loads (64 VGPR) -> one vmcnt wait
  float4 a[16];
#pragma unroll
  for (int kc = 0; kc < 8; ++kc) {
    a[2 * kc] = *(const float4*)(arow + kc * 32);
    a[2 * kc + 1] = *(const float4*)(arow + kc * 32 + 4);
  }
  // convert once to bf16 frags (32 VGPR)
  u16x8 au[8];
#pragma unroll
  for (int kc = 0; kc < 8; ++kc) {
    float4 a0 = a[2 * kc], a1 = a[2 * kc + 1];
    au[kc][0] = f2bf(a0.x); au[kc][1] = f2bf(a0.y);
    au[kc][2] = f2bf(a0.z); au[kc][3] = f2bf(a0.w);
    au[kc][4] = f2bf(a1.x); au[kc][5] = f2bf(a1.y);
    au[kc][6] = f2bf(a1.z); au[kc][7] = f2bf(a1.w);
  }

  f32x4 acc[4] = {{0.f, 0.f, 0.f, 0.f}, {0.f, 0.f, 0.f, 0.f},
                  {0.f, 0.f, 0.f, 0.f}, {0.f, 0.f, 0.f, 0.f}};
#pragma unroll
  for (int c = 0; c < 4; ++c) {
    const u16* brow = w1t + (c * 16 + mn) * IN_CH + quad * 8;
    u16x8 bu[8];  // clustered, L1-hot (B is 32 KB shared chip-wide)
#pragma unroll
    for (int kc = 0; kc < 8; ++kc) bu[kc] = *(const u16x8*)(brow + kc * 32);
#pragma unroll
    for (int kc = 0; kc < 8; ++kc)
      acc[c] = __builtin_amdgcn_mfma_f32_16x16x32_bf16(
          __builtin_bit_cast(bf16x8, au[kc]), __builtin_bit_cast(bf16x8, bu[kc]),
          acc[c], 0, 0, 0);
  }
#pragma unroll
  for (int r = 0; r < 4; ++r) {
    int row = rowbase + quad * 4 + r;
    float dv = dinv[row];
#pragma unroll
    for (int c = 0; c < 4; ++c)
      h1[(size_t)row * HID + c * 16 + mn] = f2bf(dv * acc[c][r]);
  }
}

__global__ __launch_bounds__(256) void k_gemm2(const u16* __restrict__ g1,
                                               const u16* __restrict__ w2t,
                                               const float* __restrict__ dinv,
                                               u16* __restrict__ h2) {
  int lane = threadIdx.x & 63;
  int wave = threadIdx.x >> 6;
  int rowbase = blockIdx.x * 16;
  int colbase = wave * 16;
  int mn = lane & 15, quad = lane >> 4;
  const u16* arow = g1 + (size_t)(rowbase + mn) * HID + quad * 8;
  const u16* brow = w2t + (colbase + mn) * HID + quad * 8;
  u16x8 au0 = *(const u16x8*)(arow);
  u16x8 au1 = *(const u16x8*)(arow + 32);
  u16x8 bu0 = *(const u16x8*)(brow);
  u16x8 bu1 = *(const u16x8*)(brow + 32);
  f32x4 acc = {0.f, 0.f, 0.f, 0.f};
  acc = __builtin_amdgcn_mfma_f32_16x16x32_bf16(
      __builtin_bit_cast(bf16x8, au0), __builtin_bit_cast(bf16x8, bu0), acc, 0, 0, 0);
  acc = __builtin_amdgcn_mfma_f32_16x16x32_bf16(
      __builtin_bit_cast(bf16x8, au1), __builtin_bit_cast(bf16x8, bu1), acc, 0, 0, 0);
#pragma unroll
  for (int r = 0; r < 4; ++r) {
    int row = rowbase + quad * 4 + r;
    h2[(size_t)row * HID + colbase + mn] = f2bf(dinv[row] * acc[r]);
  }
}

// ---------------- aggregation: wave per node, scalar edges, multi-accumulator ----------------
// out[i] = dinv_i * (sum_e h'[src_e] + h'[i]) + bias
// The proven 64.4us/pass form (L2-miss-transaction-bound; scalar and vector
// gather forms measured identical). launch_bounds(256,4): <=128 VGPR.

template <bool RELU, bool BF16OUT>
__global__ __launch_bounds__(256, 4) void k_agg(const u16* __restrict__ hin,
                                                const int* __restrict__ rptr,
                                                const int* __restrict__ rcnt,
                                                const u32* __restrict__ sedge,
                                                const float* __restrict__ bias,
                                                void* __restrict__ outv, int N) {
  int wid = blockIdx.x * 4 + (threadIdx.x >> 6);
  int lane = threadIdx.x & 63;
  if (wid >= N) return;
  int start = __builtin_amdgcn_readfirstlane(rptr[wid]);
  int len = __builtin_amdgcn_readfirstlane(rcnt[wid]);
  float di = rsqrtf((float)(len + 1));
  float a0 = bf2f(hin[(size_t)wid * HID + lane]);  // self-loop
  float a1 = 0.f, a2 = 0.f, a3 = 0.f;
  const u32* se = sedge + start;
  int j = 0;
  for (; j + 16 <= len; j += 16) {
    u16 v[16];
#pragma unroll
    for (int k = 0; k < 16; ++k) {
      int e = (int)(se[j + k] & 0xFFFFF);  // wave-uniform -> s_load batch
      v[k] = hin[(size_t)e * HID + lane];  // 16 gathers in flight
    }
#pragma unroll
    for (int k = 0; k < 16; ++k) {
      float f = bf2f(v[k]);
      if ((k & 3) == 0) a0 += f;
      else if ((k & 3) == 1) a1 += f;
      else if ((k & 3) == 2) a2 += f;
      else a3 += f;
    }
  }
  if (j + 8 <= len) {
    u16 v[8];
#pragma unroll
    for (int k = 0; k < 8; ++k) {
      int e = (int)(se[j + k] & 0xFFFFF);
      v[k] = hin[(size_t)e * HID + lane];
    }
#pragma unroll
    for (int k = 0; k < 8; ++k) {
      float f = bf2f(v[k]);
      if ((k & 3) == 0) a0 += f;
      else if ((k & 3) == 1) a1 += f;
      else if ((k & 3) == 2) a2 += f;
      else a3 += f;
    }
    j += 8;
  }
  if (j + 4 <= len) {
    u16 v[4];
#pragma unroll
    for (int k = 0; k < 4; ++k) {
      int e = (int)(se[j + k] & 0xFFFFF);
      v[k] = hin[(size_t)e * HID + lane];
    }
    a0 += bf2f(v[0]); a1 += bf2f(v[1]); a2 += bf2f(v[2]); a3 += bf2f(v[3]);
    j += 4;
  }
  for (; j < len; ++j) {
    int e = (int)(se[j] & 0xFFFFF);
    a0 += bf2f(hin[(size_t)e * HID + lane]);
  }
  float acc = (a0 + a1) + (a2 + a3);
  acc = di * acc + bias[lane];
  if (RELU) acc = fmaxf(acc, 0.f);
  if (BF16OUT) ((u16*)outv)[(size_t)wid * HID + lane] = f2bf(acc);
  else ((float*)outv)[(size_t)wid * HID + lane] = acc;
}

// ---------------- host ----------------

extern "C" void kernel_launch(void* const* d_in, const int* in_sizes, int n_in,
                              void* d_out, int out_size, void* d_ws, size_t ws_size,
                              hipStream_t stream) {
  const float* x = (const float*)d_in[0];
  const int* ei = (const int*)d_in[1];  // [2][E] int32
  const float* W1 = (const float*)d_in[2];
  const float* b1 = (const float*)d_in[3];
  const float* W2 = (const float*)d_in[4];
  const float* b2 = (const float*)d_in[5];
  float* out = (float*)d_out;

  const int N = in_sizes[0] / IN_CH;  // 100000
  const int E = in_sizes[1] / 2;      // 3200000
  const int* e_src = ei;
  const int* e_dst = ei + E;

  size_t off = 0;
  auto carve = [&](size_t bytes) -> char* {
    char* p = (char*)d_ws + off;
    off += (bytes + 255) & ~(size_t)255;
    return p;
  };
  int* bcnt = (int*)carve((size_t)NBUK * 4);
  u32* bedge = (u32*)carve((size_t)NBUK * BCAP * 4);  // 17.6 MB
  int* rptr = (int*)carve((size_t)N * 4);
  int* rcnt = (int*)carve((size_t)N * 4);
  float* dinv = (float*)carve((size_t)N * 4);
  u16* w1t = (u16*)carve(64 * 256 * 2);
  u16* w2t = (u16*)carve(64 * 64 * 2);
  u16* h1 = (u16*)carve((size_t)N * HID * 2);  // reused for h2
  u16* g1 = (u16*)carve((size_t)N * HID * 2);

  const int n_tiles = (E + TILE - 1) / TILE;  // 391
  const int nb_g1 = (N + 63) / 64;            // 64 rows per block (4 waves x 16)

  (void)hipMemsetAsync(bcnt, 0, (size_t)NBUK * 4, stream);
  k_wprep<<<(64 * 256 + 64 * 64 + 255) / 256, 256, 0, stream>>>(W1, W2, w1t, w2t);
  k_part<<<n_tiles, 1024, 0, stream>>>(e_src, e_dst, bcnt, bedge, E);
  k_sort<<<NBUK, 512, 0, stream>>>(bcnt, bedge, rptr, rcnt, dinv, N);
  k_gemm1<<<nb_g1, 256, 0, stream>>>(x, w1t, dinv, h1, N);
  k_agg<true, true><<<(N + 3) / 4, 256, 0, stream>>>(h1, rptr, rcnt, bedge, b1, g1, N);
  k_gemm2<<<N / 16, 256, 0, stream>>>(g1, w2t, dinv, h1);
  k_agg<false, false><<<(N + 3) / 4, 256, 0, stream>>>(h1, rptr, rcnt, bedge, b2, out, N);
}